// Round 2
// baseline (108.633 us; speedup 1.0000x reference)
//
#include <hip/hip_runtime.h>

// out[n,s,d] = sum_{l=0..7} weight[l, x[n,s,l], d]
// N=8, S=2048, L=8, K=1024, D=1024
//
// Single fused fp32 gather kernel. Structure is L2-BW-bound:
//   L2-side bytes = 512 MiB gather reads + 64 MiB out writes + 32 MiB fill
//   -> ~17.6 us floor at 34.5 TB/s aggregate L2.
// This revision removes issue-rate overhead, not bytes:
//  - All 32 gather addresses precomputed as 32-bit byte offsets against a
//    wave-uniform base -> saddr+voffset form (no per-load 64-bit adds).
//  - Index fetch: 2x ds_read_b128 per row instead of 8 scalar LDS reads.
//  - XCD-partitioned (chunk = blockIdx&7): each XCD's 4 MiB fp32 d-slice
//    stays resident in its private L2.
//  - 4 rows x 8 levels = 32 independent 16 B loads per thread, nontemporal
//    fp32 stores (no RFO on out).

#define NS      (8 * 2048)
#define LVL     8
#define KK      1024
#define DD      1024
#define NCH     8                 // d-chunks (== XCD count)
#define DCH     (DD / NCH)        // 128 floats per chunk
#define ROWSPB  32                // ns rows per block
#define THREADS 256

typedef float f32x4 __attribute__((ext_vector_type(4)));

__global__ __launch_bounds__(THREADS, 4) void multi_embedding_f32_kernel(
    const int* __restrict__ x,          // (N*S, L) int32
    const float* __restrict__ w,        // (L, K, D) fp32
    float* __restrict__ out)            // (N*S, D) fp32
{
    const int chunk = blockIdx.x & (NCH - 1);      // -> XCD id (round-robin)
    const int nsg   = blockIdx.x >> 3;
    const int tid   = threadIdx.x;
    const int ns0   = nsg * ROWSPB;

    // Stage 32 rows x 8 levels of indices: 256 ints, one 4B load per thread.
    __shared__ int sidx[ROWSPB * LVL];
    sidx[tid] = x[(size_t)ns0 * LVL + tid];
    __syncthreads();
    const int4* s4 = reinterpret_cast<const int4*>(sidx);

    const int lane = tid & 31;        // 32 lanes x 4 floats = 128 = DCH
    const int rg   = tid >> 5;        // 0..7 row-groups

    // Wave-uniform bases (SGPR) + 32-bit per-lane byte offsets.
    const char* wbase = (const char*)w   + (size_t)chunk * (DCH * 4);
    char*       obase = (char*)out       + (size_t)chunk * (DCH * 4);
    const unsigned laneoff = (unsigned)lane << 4;    // lane * 16 B

    int rows[4];
    unsigned off[4][LVL];
#pragma unroll
    for (int r = 0; r < 4; ++r) {
        rows[r] = rg + (r << 3);
        const int4 i0 = s4[rows[r] * 2];
        const int4 i1 = s4[rows[r] * 2 + 1];
        const int idx[LVL] = { i0.x, i0.y, i0.z, i0.w, i1.x, i1.y, i1.z, i1.w };
#pragma unroll
        for (int l = 0; l < LVL; ++l)
            off[r][l] = (((unsigned)((l << 10) + idx[l])) << 12) + laneoff;
    }

    f32x4 acc[4];
#pragma unroll
    for (int r = 0; r < 4; ++r)
        acc[r] = *reinterpret_cast<const f32x4*>(wbase + off[r][0]);
#pragma unroll
    for (int l = 1; l < LVL; ++l) {
#pragma unroll
        for (int r = 0; r < 4; ++r)
            acc[r] += *reinterpret_cast<const f32x4*>(wbase + off[r][l]);
    }

#pragma unroll
    for (int r = 0; r < 4; ++r) {
        const unsigned ooff = ((unsigned)(ns0 + rows[r]) << 12) + laneoff;
        __builtin_nontemporal_store(acc[r],
            reinterpret_cast<f32x4*>(obase + ooff));
    }
}

extern "C" void kernel_launch(void* const* d_in, const int* in_sizes, int n_in,
                              void* d_out, int out_size, void* d_ws, size_t ws_size,
                              hipStream_t stream) {
    const int*   x = (const int*)d_in[0];
    const float* w = (const float*)d_in[1];
    float*     out = (float*)d_out;

    // (NS/ROWSPB) groups * NCH chunks = 512 * 8 = 4096 blocks
    multi_embedding_f32_kernel<<<dim3((NS / ROWSPB) * NCH), dim3(THREADS), 0, stream>>>(x, w, out);
}